// Round 6
// baseline (49.804 us; speedup 1.0000x reference)
//
#include <hip/hip_runtime.h>

#define CIN   32
#define COUT  64
#define HH    64
#define WW    64
#define NB    4
#define P     4              // pixel rows per lane
#define WAVES 2              // waves per block
#define TH    (P * WAVES)    // 8 rows per block
#define HR    (TH + 2)       // 10 staged rows
#define SW    72             // row stride dwords (image col c at dword c+4; halo cols at 3 and 68)
#define G     8              // input channels per LDS round
#define CPT   2              // output channels per thread
#define WPAD  12             // padded dwords per 9-weight group

__global__ __launch_bounds__(128, 2)
void aeg_conv_kernel(const float* __restrict__ x,
                     const float* __restrict__ weight,
                     const float* __restrict__ conv_w,
                     const float* __restrict__ conv_b,
                     float* __restrict__ out)
{
    __shared__ float sx[HR * G * SW];            // 10*8*72*4 = 23040 B
    __shared__ float sw[2 * CPT * CIN * WPAD];   // 2*2*32*12*4 = 6144 B

    const int tid = threadIdx.x;
    const int i0  = blockIdx.x * TH;
    const int n   = blockIdx.y;
    const int co0 = blockIdx.z * CPT;

    const int tj = tid & 63;            // column
    const int ri = (tid >> 6) * P;      // first pixel row (within tile) for this lane
    const int pbase = (i0 + ri + tj) & 1;   // parity of first owned pixel

    const float* xn = x + (size_t)n * (CIN * HH * WW);

    // halo columns (image cols -1,64 -> dwords 3,68) are always zero: write once
    for (int idx = tid; idx < HR * G * 2; idx += 128) {
        int pair = idx >> 1;
        int col  = (idx & 1) ? 68 : 3;
        sx[pair * SW + col] = 0.0f;
    }

    // ---- stage this block's weight slice into LDS (128 groups, 1 per thread) ----
    {
        int s  = tid >> 6;              // 0 = aeg weight, 1 = conv weight
        int c2 = (tid >> 5) & 1;        // co within chunk
        int ci = tid & 31;
        const float* src = (s ? conv_w : weight) + ((size_t)(co0 + c2) * CIN + ci) * 9;
        float* dst = &sw[((s * CPT + c2) * CIN + ci) * WPAD];
        #pragma unroll
        for (int k = 0; k < 9; ++k) dst[k] = src[k];
    }

    float aeg[P][CPT], cv[P][CPT];
    #pragma unroll
    for (int p = 0; p < P; ++p)
        #pragma unroll
        for (int c = 0; c < CPT; ++c) { aeg[p][c] = 0.0f; cv[p][c] = 0.0f; }

    for (int g = 0; g < CIN; g += G) {
        __syncthreads();                // previous round's readers done (also covers init writes)
        // ---- stage G channels x HR rows: 10 iters of float4 load + b128 LDS write ----
        #pragma unroll
        for (int it = 0; it < 10; ++it) {
            int idx   = it * 128 + tid;       // 0..1279
            int pair  = idx >> 4;             // r*G + cl, 0..79
            int lane4 = idx & 15;             // 16B chunk within row
            int r     = pair >> 3;
            int cl    = pair & 7;
            int gi    = i0 - 1 + r;
            float4 v = make_float4(0.f, 0.f, 0.f, 0.f);
            if ((unsigned)gi < (unsigned)HH)
                v = *(const float4*)&xn[(g + cl) * (HH * WW) + gi * WW + lane4 * 4];
            *(float4*)&sx[pair * SW + 4 + lane4 * 4] = v;
        }
        __syncthreads();

        #pragma unroll 2
        for (int cl = 0; cl < G; ++cl) {
            const int ci = g + cl;
            // 18 taps cover the 3x3 windows of 4 stacked pixel rows
            float t[P + 2][3];
            #pragma unroll
            for (int rr = 0; rr < P + 2; ++rr)
                #pragma unroll
                for (int kj = 0; kj < 3; ++kj)
                    t[rr][kj] = sx[((ri + rr) * G + cl) * SW + 3 + tj + kj];

            #pragma unroll
            for (int c = 0; c < CPT; ++c) {
                float wA[12], wC[12];
                const float* pa = &sw[((size_t)c * CIN + ci) * WPAD];
                const float* pc = &sw[((size_t)(CPT + c) * CIN + ci) * WPAD];
                *(float4*)&wA[0] = *(const float4*)&pa[0];
                *(float4*)&wA[4] = *(const float4*)&pa[4];
                *(float4*)&wA[8] = *(const float4*)&pa[8];
                *(float4*)&wC[0] = *(const float4*)&pc[0];
                *(float4*)&wC[4] = *(const float4*)&pc[4];
                *(float4*)&wC[8] = *(const float4*)&pc[8];

                float r[P] = {0.0f, 0.0f, 0.0f, 0.0f};
                #pragma unroll
                for (int k = 0; k < 9; ++k) {
                    float yv = wA[k];
                    float yc = wC[k];
                    #pragma unroll
                    for (int p = 0; p < P; ++p) {
                        float tv = t[p + k / 3][k % 3];
                        // parity of (i+j+k) for pixel p: pbase ^ (p&1) ^ (k&1)
                        bool so = ((pbase ^ p ^ k) & 1) != 0;
                        float b = so ? tv : yv;     // odd: r=(r+y)*t ; even: r=(r+t)*y
                        r[p] = fmaf(r[p], b, tv * yv);
                        cv[p][c] = fmaf(tv, yc, cv[p][c]);
                    }
                }
                #pragma unroll
                for (int p = 0; p < P; ++p) aeg[p][c] += r[p];
            }
        }
    }

    // ---- epilogue: sigmoid(aeg) * (conv + bias) ----
    #pragma unroll
    for (int p = 0; p < P; ++p) {
        int i = i0 + ri + p;
        #pragma unroll
        for (int c = 0; c < CPT; ++c) {
            int co = co0 + c;
            float conv = cv[p][c] + conv_b[co];
            float sg = 1.0f / (1.0f + __expf(-aeg[p][c]));
            out[(((size_t)n * COUT + co) * HH + i) * WW + tj] = sg * conv;
        }
    }
}

extern "C" void kernel_launch(void* const* d_in, const int* in_sizes, int n_in,
                              void* d_out, int out_size, void* d_ws, size_t ws_size,
                              hipStream_t stream) {
    const float* x      = (const float*)d_in[0];
    const float* weight = (const float*)d_in[1];
    const float* conv_w = (const float*)d_in[2];
    const float* conv_b = (const float*)d_in[3];
    float* out = (float*)d_out;

    dim3 grid(HH / TH, NB, COUT / CPT);   // 8 x 4 x 32 = 1024 blocks
    aeg_conv_kernel<<<grid, 128, 0, stream>>>(x, weight, conv_w, conv_b, out);
}

// Round 7
// 34.978 us; speedup vs baseline: 1.4239x; 1.4239x over previous
//
#include <hip/hip_runtime.h>

#define CIN   32
#define COUT  64
#define HH    64
#define WW    64
#define NB    4
#define TH    8              // rows per block
#define HR    (TH + 2)       // 10 staged rows
#define G     8              // input channels per LDS round
#define CPT   2              // output channels per thread
#define WPAD  12             // padded dwords per 9-weight group
#define ROWCI 72             // dwords per (row, ci): two 36-dword parity arrays
// parity array layout (36 dwords): [0]=left halo (col -1), [1..32]=cols, [33]=right halo (col 64)

template<int S>
__device__ __forceinline__ void math_g(const float* __restrict__ sx,
                                       const float* __restrict__ sw,
                                       int lrow, int m, int cb, int g,
                                       float aeg[2][CPT], float cv[2][CPT])
{
    #pragma unroll 2
    for (int cl = 0; cl < G; ++cl) {
        const int ci = g + cl;
        // 15 taps: 5 window rows x (center b32 + side pair -> ds_read2_b32)
        float tc[5], tl[5], tr[5];
        #pragma unroll
        for (int wr = 0; wr < 5; ++wr) {
            const int qc = (wr & 1) ^ 1 ^ S;              // compile-time array select
            const float* rowp = sx + (lrow + wr) * (G * ROWCI) + cl * ROWCI;
            tc[wr] = rowp[qc * 36 + 1 + m];
            const float* sp = rowp + (1 - qc) * 36 + m + cb;
            tl[wr] = sp[0];
            tr[wr] = sp[1];
        }
        #pragma unroll
        for (int c = 0; c < CPT; ++c) {
            float wA[12], wC[12];
            const float* pa = &sw[(c * CIN + ci) * WPAD];
            const float* pc = &sw[((CPT + c) * CIN + ci) * WPAD];
            *(float4*)&wA[0] = *(const float4*)&pa[0];
            *(float4*)&wA[4] = *(const float4*)&pa[4];
            *(float4*)&wA[8] = *(const float4*)&pa[8];
            *(float4*)&wC[0] = *(const float4*)&pc[0];
            *(float4*)&wC[4] = *(const float4*)&pc[4];
            *(float4*)&wC[8] = *(const float4*)&pc[8];

            #pragma unroll
            for (int p = 0; p < 2; ++p) {
                float r = 0.0f;
                #pragma unroll
                for (int k = 0; k < 9; ++k) {
                    const int wr = 2 * p + k / 3;
                    const int kj = k % 3;
                    const float t = (kj == 0) ? tl[wr] : ((kj == 1) ? tc[wr] : tr[wr]);
                    const float prod = t * wA[k];
                    // pixel parity == S -> step parity = S^(k&1); even: r=(r+t)*y, odd: r=(r+y)*t
                    r = ((k & 1) == S) ? fmaf(r, wA[k], prod) : fmaf(r, t, prod);
                    cv[p][c] = fmaf(t, wC[k], cv[p][c]);
                }
                aeg[p][c] += r;
            }
        }
    }
}

__global__ __launch_bounds__(256, 4)
void aeg_conv_kernel(const float* __restrict__ x,
                     const float* __restrict__ weight,
                     const float* __restrict__ conv_w,
                     const float* __restrict__ conv_b,
                     float* __restrict__ out)
{
    __shared__ float sx[HR * G * ROWCI];          // 10*8*72*4 = 23040 B
    __shared__ float sw[2 * CPT * CIN * WPAD];    // 2*2*32*12*4 = 6144 B

    const int tid = threadIdx.x;
    const int i0  = blockIdx.x * TH;
    const int n   = blockIdx.y;
    const int co0 = blockIdx.z * CPT;

    const int s  = (tid >> 6) & 1;      // wave parity class
    const int rg = tid >> 7;            // row group (0,1)
    const int h  = (tid >> 5) & 1;      // half-wave -> row offset
    const int m  = tid & 31;

    const int rb_local = rg * 4 + h;            // local first pixel row: {0,1,4,5}; owns +0,+2
    const int rb  = i0 + rb_local;              // absolute first pixel row
    const int cb  = (rb & 1) ^ s;               // column LSB for this lane's class
    const int col = 2 * m + cb;                 // owned column (both pixel rows)

    const float* xn = x + (size_t)n * (CIN * HH * WW);

    // ---- zero the halo-column slots (0 and 33) of every parity array, once ----
    for (int idx = tid; idx < HR * G * 2 * 2; idx += 256) {
        int arr  = idx >> 1;                    // 0..159
        int slot = (idx & 1) ? 33 : 0;
        sx[arr * 36 + slot] = 0.0f;
    }

    // ---- stage this block's weight slice into LDS (128 groups) ----
    if (tid < 128) {
        int set = tid >> 6;                     // 0 = aeg, 1 = conv
        int c2  = (tid >> 5) & 1;
        int ci  = tid & 31;
        const float* src = (set ? conv_w : weight) + ((size_t)(co0 + c2) * CIN + ci) * 9;
        float* dst = &sw[((set * CPT + c2) * CIN + ci) * WPAD];
        #pragma unroll
        for (int k = 0; k < 9; ++k) dst[k] = src[k];
    }

    float aeg[2][CPT], cv[2][CPT];
    #pragma unroll
    for (int p = 0; p < 2; ++p)
        #pragma unroll
        for (int c = 0; c < CPT; ++c) { aeg[p][c] = 0.0f; cv[p][c] = 0.0f; }

    for (int g = 0; g < CIN; g += G) {
        __syncthreads();                // previous readers done (also covers init writes)
        // ---- stage HR rows x G ci, parity-split: 5 iters of float4 + 4 b32 writes ----
        #pragma unroll
        for (int it = 0; it < 5; ++it) {
            int idx  = it * 256 + tid;          // 0..1279
            int f4   = idx & 15;                // 16B chunk within row
            int pair = idx >> 4;                // r10*G + cl, 0..79
            int r10  = pair >> 3;
            int cl   = pair & 7;
            int gi   = i0 - 1 + r10;
            float4 v = make_float4(0.f, 0.f, 0.f, 0.f);
            if ((unsigned)gi < (unsigned)HH)
                v = *(const float4*)&xn[(g + cl) * (HH * WW) + gi * WW + 4 * f4];
            int rp   = gi & 1;                  // parity array holding even-offset cols
            float* base = &sx[pair * ROWCI];
            base[rp * 36 + 1 + 2 * f4]        = v.x;   // col 4f4
            base[rp * 36 + 2 + 2 * f4]        = v.z;   // col 4f4+2
            base[(rp ^ 1) * 36 + 1 + 2 * f4]  = v.y;   // col 4f4+1
            base[(rp ^ 1) * 36 + 2 + 2 * f4]  = v.w;   // col 4f4+3
        }
        __syncthreads();

        if (s == 0) math_g<0>(sx, sw, rb_local, m, cb, g, aeg, cv);
        else        math_g<1>(sx, sw, rb_local, m, cb, g, aeg, cv);
    }

    // ---- epilogue: sigmoid(aeg) * (conv + bias) ----
    #pragma unroll
    for (int p = 0; p < 2; ++p) {
        int i = rb + 2 * p;
        #pragma unroll
        for (int c = 0; c < CPT; ++c) {
            int co = co0 + c;
            float conv = cv[p][c] + conv_b[co];
            float sg = 1.0f / (1.0f + __expf(-aeg[p][c]));
            out[(((size_t)n * COUT + co) * HH + i) * WW + col] = sg * conv;
        }
    }
}

extern "C" void kernel_launch(void* const* d_in, const int* in_sizes, int n_in,
                              void* d_out, int out_size, void* d_ws, size_t ws_size,
                              hipStream_t stream) {
    const float* x      = (const float*)d_in[0];
    const float* weight = (const float*)d_in[1];
    const float* conv_w = (const float*)d_in[2];
    const float* conv_b = (const float*)d_in[3];
    float* out = (float*)d_out;

    dim3 grid(HH / TH, NB, COUT / CPT);   // 8 x 4 x 32 = 1024 blocks
    aeg_conv_kernel<<<grid, 256, 0, stream>>>(x, weight, conv_w, conv_b, out);
}